// Round 20
// baseline (135.745 us; speedup 1.0000x reference)
//
#include <hip/hip_runtime.h>
#include <hip/hip_fp16.h>

typedef _Float16 f16;
typedef f16 f16x8 __attribute__((ext_vector_type(8)));
typedef f16 f16x4 __attribute__((ext_vector_type(4)));
typedef f16 f16x2 __attribute__((ext_vector_type(2)));
typedef float f32x4 __attribute__((ext_vector_type(4)));

#define DEVI static __device__ __forceinline__

constexpr int Bc = 2, Lc = 1024, Dc = 1024, Hc = 16, DKc = 64, Rc = 130;
constexpr float SCALE = 0.07216878364870323f; // 1/sqrt(64*3)
constexpr float MASKV = -30000.0f;            // f16-safe "-inf" (f16-exact)

DEVI uint2 pack8(int4 a, int4 b) {
    unsigned lo = (unsigned)(a.x & 255) | ((unsigned)(a.y & 255) << 8) |
                  ((unsigned)(a.z & 255) << 16) | ((unsigned)(a.w & 255) << 24);
    unsigned hi = (unsigned)(b.x & 255) | ((unsigned)(b.y & 255) << 8) |
                  ((unsigned)(b.z & 255) << 16) | ((unsigned)(b.w & 255) << 24);
    return make_uint2(lo, hi);
}

DEVI int i4get(const int4& v, int u) {  // compile-time u under unroll -> no scratch
    return u == 0 ? v.x : (u == 1 ? v.y : (u == 2 ? v.z : v.w));
}

DEVI int packf16(float a, float b) {
    f16x2 t = {(f16)a, (f16)b};
    return __builtin_bit_cast(int, t);
}

// ---------------------------------------------------------------------------
// Fused QKV GEMM, f32 inputs staged to f16 LDS. Tile 128x128 (A-tile re-read
// redundancy halved vs 128x64), BK=32, 4 waves (2x2), each wave 64x64.
// q pre-scaled by SCALE. q/k -> [B,H,L,DK]; v -> [B,H,DK,L] transposed.
// ---------------------------------------------------------------------------
__global__ __launch_bounds__(256) void gemm_qkv(const float* __restrict__ A,
                                                const float* __restrict__ wq,
                                                const float* __restrict__ wk,
                                                const float* __restrict__ wv,
                                                const float* __restrict__ bq,
                                                const float* __restrict__ bk,
                                                const float* __restrict__ bv,
                                                f16* __restrict__ qw,
                                                f16* __restrict__ kw,
                                                f16* __restrict__ vtw) {
    constexpr int K = 1024;
    __shared__ __align__(16) f16 As[128][40];
    __shared__ __align__(16) f16 Bs[128][40];
    const int tid = threadIdx.x, lane = tid & 63, w = tid >> 6;
    const int wm = w >> 1, wn = w & 1;
    const int g = lane >> 4, il16 = lane & 15;
    const int m0 = blockIdx.y * 128, n0 = blockIdx.x * 128;
    const int which = n0 >> 10;  // 0=q 1=k 2=v (uniform per block; 1024%128==0)
    const float* __restrict__ W = which == 0 ? wq : (which == 1 ? wk : wv);
    const int n0L = n0 & 1023;

    f32x4 acc[4][4];
#pragma unroll
    for (int i = 0; i < 4; ++i)
#pragma unroll
        for (int j = 0; j < 4; ++j) acc[i][j] = (f32x4){0.f, 0.f, 0.f, 0.f};

    for (int k0 = 0; k0 < K; k0 += 32) {
#pragma unroll
        for (int rep = 0; rep < 4; ++rep) {  // A 128x32 f32 -> f16
            int id = tid + rep * 256;
            int row = id >> 3, c = (id & 7) * 4;
            float4 v = *(const float4*)&A[(size_t)(m0 + row) * K + k0 + c];
            *(f16x4*)&As[row][c] = (f16x4){(f16)v.x, (f16)v.y, (f16)v.z, (f16)v.w};
        }
#pragma unroll
        for (int rep = 0; rep < 4; ++rep) {  // W 128x32 f32 -> f16
            int id = tid + rep * 256;
            int row = id >> 3, c = (id & 7) * 4;
            float4 v = *(const float4*)&W[(size_t)(n0L + row) * K + k0 + c];
            *(f16x4*)&Bs[row][c] = (f16x4){(f16)v.x, (f16)v.y, (f16)v.z, (f16)v.w};
        }
        __syncthreads();
        f16x8 a[4], bb[4];
#pragma unroll
        for (int mf = 0; mf < 4; ++mf)
            a[mf] = *(const f16x8*)&As[wm * 64 + mf * 16 + il16][g * 8];
#pragma unroll
        for (int nf = 0; nf < 4; ++nf)
            bb[nf] = *(const f16x8*)&Bs[wn * 64 + nf * 16 + il16][g * 8];
#pragma unroll
        for (int mf = 0; mf < 4; ++mf)
#pragma unroll
            for (int nf = 0; nf < 4; ++nf)
                acc[mf][nf] = __builtin_amdgcn_mfma_f32_16x16x32_f16(a[mf], bb[nf], acc[mf][nf], 0, 0, 0);
        __syncthreads();
    }

    const float* bp = which == 0 ? bq : (which == 1 ? bk : bv);
    const float scl = which == 0 ? SCALE : 1.0f;
#pragma unroll
    for (int mf = 0; mf < 4; ++mf)
#pragma unroll
        for (int nf = 0; nf < 4; ++nf) {
            int rowb = m0 + wm * 64 + mf * 16 + g * 4;
            int col = n0 + wn * 64 + nf * 16 + il16;
            int colL = col & 1023;
            int h = colL >> 6, d = colL & 63;
            float bv_ = bp[colL];
            if (which == 2) {
                int b = rowb >> 10, i = rowb & (Lc - 1);
                f16x4 pk = {(f16)(acc[mf][nf][0] + bv_), (f16)(acc[mf][nf][1] + bv_),
                            (f16)(acc[mf][nf][2] + bv_), (f16)(acc[mf][nf][3] + bv_)};
                *(f16x4*)&vtw[(((size_t)(b * Hc + h)) * DKc + d) * Lc + i] = pk;
            } else {
                f16* dst = which ? kw : qw;
#pragma unroll
                for (int rg = 0; rg < 4; ++rg) {
                    int row = rowb + rg;
                    int b = row >> 10, i = row & (Lc - 1);
                    dst[(((size_t)(b * Hc + h)) * Lc + i) * DKc + d] =
                        (f16)((acc[mf][nf][rg] + bv_) * scl);
                }
            }
        }
}

// ---------------------------------------------------------------------------
// rel tables via MFMA, both tables in one launch (z selects):
//   z=0: c2pT  = qw . rel_k^T          (qw pre-scaled -> scl=1, no mask)
//   z=1: p2c   = SCALE * kw . rel_q^T  (+ MASKV folded per masked column)
// grid (L/64, B*H, 2).
// ---------------------------------------------------------------------------
__global__ __launch_bounds__(256) void rel_mfma(const f16* __restrict__ qw,
                                                const f16* __restrict__ kw,
                                                const float* __restrict__ rel_k,
                                                const float* __restrict__ rel_q,
                                                f16* __restrict__ c2pTw,
                                                f16* __restrict__ p2cw,
                                                const int* __restrict__ mask) {
    __shared__ __align__(16) f16 As[144][72];
    __shared__ __align__(16) f16 Bs[64][72];
    const int tid = threadIdx.x, lane = tid & 63, w = tid >> 6;
    const int bh = blockIdx.y, h = bh & (Hc - 1);
    const int i0 = blockIdx.x * 64;
    const int z = blockIdx.z;
    const size_t bhR = (size_t)bh * Rc;
    const f16* __restrict__ rowmat = z ? kw : qw;
    const float* __restrict__ relmat = z ? rel_q : rel_k;
    f16* __restrict__ outT = z ? p2cw : c2pTw;
    const float scl = z ? SCALE : 1.0f;

    for (int e = tid; e < Rc * 16; e += 256) {
        int r = e >> 4, c = (e & 15) * 4;
        float4 v = *(const float4*)&relmat[((size_t)h * Rc + r) * DKc + c];
        *(f16x4*)&As[r][c] = (f16x4){(f16)v.x, (f16)v.y, (f16)v.z, (f16)v.w};
    }
    if (tid < 224) {
        int r = 130 + (tid >> 4), c = (tid & 15) * 4;
        *(f16x4*)&As[r][c] = (f16x4){(f16)0.f, (f16)0.f, (f16)0.f, (f16)0.f};
    }
    for (int e = tid; e < 64 * 8; e += 256) {
        int i = e >> 3, c = (e & 7) * 8;
        *(f16x8*)&Bs[i][c] = *(const f16x8*)&rowmat[((size_t)bh * Lc + i0 + i) * DKc + c];
    }
    __syncthreads();

    // per-thread output column; mask-fold value (p2c table only)
    const int ocol = i0 + w * 16 + (lane & 15);
    float ma = 0.f;
    if (z) ma = mask[(bh >> 4) * Lc + ocol] ? MASKV : 0.f;

    f16x8 bfr[2];
#pragma unroll
    for (int ks = 0; ks < 2; ++ks)
        bfr[ks] = *(const f16x8*)&Bs[w * 16 + (lane & 15)][ks * 32 + (lane >> 4) * 8];
    f32x4 acc[9];
#pragma unroll
    for (int m = 0; m < 9; ++m) acc[m] = (f32x4){0.f, 0.f, 0.f, 0.f};
#pragma unroll
    for (int m = 0; m < 9; ++m)
#pragma unroll
        for (int ks = 0; ks < 2; ++ks) {
            f16x8 af = *(const f16x8*)&As[m * 16 + (lane & 15)][ks * 32 + (lane >> 4) * 8];
            acc[m] = __builtin_amdgcn_mfma_f32_16x16x32_f16(af, bfr[ks], acc[m], 0, 0, 0);
        }
#pragma unroll
    for (int m = 0; m < 9; ++m)
#pragma unroll
        for (int rg = 0; rg < 4; ++rg) {
            int r = m * 16 + (lane >> 4) * 4 + rg;
            if (r < Rc)
                outT[(bhR + r) * Lc + ocol] = (f16)(acc[m][rg] * scl + ma);
        }
}

// ---------------------------------------------------------------------------
// attn_v10 (r19-proven): fused gather+flash, K/V cooperative dbuf LDS staging,
// P redistribution via shfl, mask folded into p2c, exact defer-rescale,
// setprio on MFMA clusters. XCD-aware flat grid: flat = ib*64 + sp*32 + bh.
// ---------------------------------------------------------------------------
__global__ __launch_bounds__(512) void attn_v10(const f16* __restrict__ q,
                                                const f16* __restrict__ k,
                                                const f16* __restrict__ vt,
                                                const f16* __restrict__ p2c,
                                                const f16* __restrict__ c2pT,
                                                const int* __restrict__ pos,
                                                f16* __restrict__ opart,
                                                float2* __restrict__ mlpart) {
    __shared__ f16 tc2p[Rc][132];               // [r][i-local 0..127] 34.3KB
    __shared__ f16 tp2c[2][Rc][36];             // [r][j-local], dbuf  18.7KB
    __shared__ __align__(16) f16 Ks[2][32][72]; // K tile, dbuf         9.2KB
    __shared__ __align__(16) f16 Vs[2][64][40]; // V tile, dbuf        10.2KB
    __shared__ unsigned char pJI[2][32][136];   // [j][i], dbuf         8.7KB

    const int tid = threadIdx.x, lane = tid & 63, w = tid >> 6;
    const int flat = blockIdx.x;
    const int ib = flat >> 6;            // 0..7
    const int sp = (flat >> 5) & 1;      // 0..1
    const int bh = flat & 31;            // 0..31
    const int b = bh >> 4, h = bh & 15;
    const int i0 = ib * 128;
    const int j0base = sp * 512;
    const size_t bhL = (size_t)bh * Lc;
    const size_t bhR = (size_t)bh * Rc;
    f16* __restrict__ op = opart + (size_t)sp * Bc * Lc * Dc;
    float2* __restrict__ mlp = mlpart + (size_t)sp * Bc * Hc * Lc;
    const int g = lane >> 4, il16 = lane & 15, irow = w * 16 + il16;

    // block-lifetime: tc2p [130][128]
    for (int e = tid; e < Rc * 32; e += 512) {
        int r = e >> 5, c4 = (e & 31) * 4;
        *(f16x4*)&tc2p[r][c4] = *(const f16x4*)&c2pT[(bhR + r) * Lc + i0 + c4];
    }

    // Q fragments (B-operand of swapped QK^T)
    f16x8 qa[2];
    {
        const f16* qp = &q[(bhL + i0 + irow) * DKc + g * 8];
        qa[0] = *(const f16x8*)qp;
        qa[1] = *(const f16x8*)(qp + 32);
    }

    float mrun = -1e30f, lrun = 0.f;
    f32x4 oacc[4];
#pragma unroll
    for (int df = 0; df < 4; ++df) oacc[df] = (f32x4){0.f, 0.f, 0.f, 0.f};

    // register pipeline state
    f16x4 kreg, vreg;                    // cooperative K/V stage (4KB each)
    int4 prA0, prA1, prB0, prB1;         // own-row pos (r1)
    f16x4 tpr0, tpr1, tpr2;              // tp2c staging regs
    uint2 pjreg;                         // pJI staging

#define FV_ISSUE(J0X)                                                                        \
    {                                                                                        \
        kreg = *(const f16x4*)&k[(bhL + (J0X) + (tid >> 4)) * DKc + (tid & 15) * 4];         \
        vreg = *(const f16x4*)&vt[((size_t)bh * DKc + (tid >> 3)) * Lc + (J0X) + (tid & 7) * 4]; \
        {                                                                                    \
            int e_ = tid;                                                                    \
            tpr0 = *(const f16x4*)&p2c[(bhR + (e_ >> 3)) * Lc + (J0X) + (e_ & 7) * 4];       \
            e_ = tid + 512;                                                                  \
            tpr1 = *(const f16x4*)&p2c[(bhR + (e_ >> 3)) * Lc + (J0X) + (e_ & 7) * 4];       \
            if (tid < 16) {                                                                  \
                e_ = tid + 1024;                                                             \
                tpr2 = *(const f16x4*)&p2c[(bhR + (e_ >> 3)) * Lc + (J0X) + (e_ & 7) * 4];   \
            }                                                                                \
        }                                                                                    \
        {                                                                                    \
            const int* pp = &pos[(bhL + (J0X) + (tid >> 4)) * Lc + i0 + (tid & 15) * 8];     \
            pjreg = pack8(*(const int4*)pp, *(const int4*)(pp + 4));                         \
        }                                                                                    \
        {                                                                                    \
            const int* prow = &pos[(bhL + i0 + irow) * Lc + (J0X) + g * 4];                  \
            prB0 = *(const int4*)prow;                                                       \
            prB1 = *(const int4*)(prow + 16);                                                \
        }                                                                                    \
    }

#define FV_COMMIT(NB)                                                                        \
    {                                                                                        \
        *(f16x4*)&Ks[NB][tid >> 4][(tid & 15) * 4] = kreg;                                   \
        *(f16x4*)&Vs[NB][tid >> 3][(tid & 7) * 4] = vreg;                                    \
        int e_ = tid;                                                                        \
        *(f16x4*)&tp2c[NB][e_ >> 3][(e_ & 7) * 4] = tpr0;                                    \
        e_ = tid + 512;                                                                      \
        *(f16x4*)&tp2c[NB][e_ >> 3][(e_ & 7) * 4] = tpr1;                                    \
        if (tid < 16) { e_ = tid + 1024; *(f16x4*)&tp2c[NB][e_ >> 3][(e_ & 7) * 4] = tpr2; } \
        *(uint2*)&pJI[NB][tid >> 4][(tid & 15) * 8] = pjreg;                                 \
    }

    // prologue: tile 0
    FV_ISSUE(j0base);
    FV_COMMIT(0);
    prA0 = prB0; prA1 = prB1;
    __syncthreads();

    for (int t = 0; t < 16; ++t) {
        const int cur = t & 1;
        const int j0 = j0base + t * 32;
        if (t < 15) FV_ISSUE(j0 + 32);

        // QK^T swapped: mfma(A=K from LDS, B=Q)
        f32x4 s[2];
        s[0] = (f32x4){0.f, 0.f, 0.f, 0.f};
        s[1] = (f32x4){0.f, 0.f, 0.f, 0.f};
        __builtin_amdgcn_s_setprio(1);
#pragma unroll
        for (int jf = 0; jf < 2; ++jf)
#pragma unroll
            for (int ks = 0; ks < 2; ++ks) {
                f16x8 kb = *(const f16x8*)&Ks[cur][jf * 16 + il16][ks * 32 + g * 8];
                s[jf] = __builtin_amdgcn_mfma_f32_16x16x32_f16(kb, qa[ks], s[jf], 0, 0, 0);
            }
        __builtin_amdgcn_s_setprio(0);

        // score assembly: r1 from registers, r2 + tables from LDS (mask folded)
        float sv[8];
#pragma unroll
        for (int u = 0; u < 8; ++u) {
            int jcol = (u < 4) ? (g * 4 + u) : (16 + g * 4 + (u - 4));
            int r1 = (u < 4) ? i4get(prA0, u) : i4get(prA1, u - 4);
            int r2 = pJI[cur][jcol][irow];
            sv[u] = s[u >> 2][u & 3] + (float)tp2c[cur][r1][jcol] + (float)tc2p[r2][irow];
        }

        // per-lane-row online softmax with exact defer-rescale
        float tm = sv[0];
#pragma unroll
        for (int e = 1; e < 8; ++e) tm = fmaxf(tm, sv[e]);
        tm = fmaxf(tm, __shfl_xor(tm, 16));
        tm = fmaxf(tm, __shfl_xor(tm, 32));
        if (__any(tm > mrun)) {
            float mnew = fmaxf(mrun, tm);
            float alpha = __expf(mrun - mnew);
            mrun = mnew;
            lrun *= alpha;
            float al[4];
#pragma unroll
            for (int rg = 0; rg < 4; ++rg)
                al[rg] = __shfl(alpha, (lane & 48) | (g * 4 + rg));
#pragma unroll
            for (int df = 0; df < 4; ++df)
#pragma unroll
                for (int rg = 0; rg < 4; ++rg) oacc[df][rg] *= al[rg];
        }
        float rs = 0.f;
#pragma unroll
        for (int e = 0; e < 8; ++e) {
            sv[e] = __expf(sv[e] - mrun);
            rs += sv[e];
        }
        rs += __shfl_xor(rs, 16);
        rs += __shfl_xor(rs, 32);
        lrun += rs;

        // P fragment redistribution via shfl (lane (g,il16) needs P[il16][g*8..+7])
        int lo0 = packf16(sv[0], sv[1]), lo1 = packf16(sv[2], sv[3]);
        int hi0 = packf16(sv[4], sv[5]), hi1 = packf16(sv[6], sv[7]);
        int s0 = ((g & 1) << 5) | il16, s1 = s0 + 16;
        int a0 = __shfl(lo0, s0), a1 = __shfl(lo1, s0);
        int a2 = __shfl(lo0, s1), a3 = __shfl(lo1, s1);
        int b0 = __shfl(hi0, s0), b1 = __shfl(hi1, s0);
        int b2 = __shfl(hi0, s1), b3 = __shfl(hi1, s1);
        int4 paw = (g < 2) ? make_int4(a0, a1, a2, a3) : make_int4(b0, b1, b2, b3);
        f16x8 pa = __builtin_bit_cast(f16x8, paw);

        // PV: A = P frags (regs), B = V tile (LDS)
        __builtin_amdgcn_s_setprio(1);
#pragma unroll
        for (int df = 0; df < 4; ++df) {
            f16x8 vb = *(const f16x8*)&Vs[cur][df * 16 + il16][g * 8];
            oacc[df] = __builtin_amdgcn_mfma_f32_16x16x32_f16(pa, vb, oacc[df], 0, 0, 0);
        }
        __builtin_amdgcn_s_setprio(0);

        if (t < 15) {
            FV_COMMIT(cur ^ 1);
            prA0 = prB0; prA1 = prB1;
        }
        __syncthreads();
    }

    // unnormalized partial (f16) + (m,l)
#pragma unroll
    for (int df = 0; df < 4; ++df)
#pragma unroll
        for (int rg = 0; rg < 4; ++rg) {
            int i = i0 + w * 16 + g * 4 + rg;
            int d = df * 16 + il16;
            op[((size_t)(b * Lc + i) * Hc + h) * DKc + d] = (f16)oacc[df][rg];
        }
    if (g == 0) mlp[bhL + i0 + irow] = make_float2(mrun, lrun);
#undef FV_ISSUE
#undef FV_COMMIT
}

// ---------------------------------------------------------------------------
// merge ns partial slots -> ctx f16 (f16x4 per thread)
// ---------------------------------------------------------------------------
__global__ __launch_bounds__(256) void merge_ns(const f16* __restrict__ op,
                                                const float2* __restrict__ ml,
                                                f16* __restrict__ ctx, int ns) {
    int t4 = blockIdx.x * 256 + threadIdx.x;  // 4-elem index, total 524288
    int t = t4 * 4;
    int b = t >> 20;
    int rem = t & 1048575;
    int i = rem >> 10;
    int h = (rem & 1023) >> 6;
    int row = ((b << 4) + h) * Lc + i;
    const size_t On = (size_t)Bc * Lc * Dc, Mn = (size_t)Bc * Hc * Lc;
    float mx = -1e30f;
    for (int s = 0; s < ns; ++s) mx = fmaxf(mx, ml[s * Mn + row].x);
    float l = 0.f;
    float v[4] = {0.f, 0.f, 0.f, 0.f};
    for (int s = 0; s < ns; ++s) {
        float2 m = ml[s * Mn + row];
        float w_ = __expf(m.x - mx);
        l += m.y * w_;
        f16x4 o = *(const f16x4*)&op[s * On + t];
#pragma unroll
        for (int e = 0; e < 4; ++e) v[e] += (float)o[e] * w_;
    }
    float rl = 1.0f / l;
    f16x4 r = {(f16)(v[0] * rl), (f16)(v[1] * rl), (f16)(v[2] * rl), (f16)(v[3] * rl)};
    *(f16x4*)&ctx[t] = r;
}

// ---------------------------------------------------------------------------
// out-proj GEMM: A f16, W f32 (staged to f16) -> f32 out
// ---------------------------------------------------------------------------
__global__ __launch_bounds__(256) void gemm_out(const f16* __restrict__ A,
                                                const float* __restrict__ W,
                                                const float* __restrict__ bias,
                                                float* __restrict__ outf) {
    constexpr int K = 1024;
    __shared__ __align__(16) f16 As[128][40];
    __shared__ __align__(16) f16 Bs[64][40];
    const int tid = threadIdx.x, lane = tid & 63, w = tid >> 6;
    const int wm = w >> 1, wn = w & 1;
    const int m0 = blockIdx.y * 128, n0 = blockIdx.x * 64;

    f32x4 acc[4][2];
#pragma unroll
    for (int i = 0; i < 4; ++i)
#pragma unroll
        for (int j = 0; j < 2; ++j) acc[i][j] = (f32x4){0.f, 0.f, 0.f, 0.f};

    for (int k0 = 0; k0 < K; k0 += 32) {
#pragma unroll
        for (int rep = 0; rep < 2; ++rep) {
            int id = tid + rep * 256;
            int row = id >> 2, c = (id & 3) * 8;
            *(f16x8*)&As[row][c] = *(const f16x8*)&A[(size_t)(m0 + row) * K + k0 + c];
        }
#pragma unroll
        for (int rep = 0; rep < 2; ++rep) {  // W 64x32 f32 -> f16
            int id = tid + rep * 256;
            int row = id >> 3, c = (id & 7) * 4;
            float4 v = *(const float4*)&W[(size_t)(n0 + row) * K + k0 + c];
            *(f16x4*)&Bs[row][c] = (f16x4){(f16)v.x, (f16)v.y, (f16)v.z, (f16)v.w};
        }
        __syncthreads();
        f16x8 a[4], bb[2];
#pragma unroll
        for (int mf = 0; mf < 4; ++mf)
            a[mf] = *(const f16x8*)&As[wm * 64 + mf * 16 + (lane & 15)][(lane >> 4) * 8];
#pragma unroll
        for (int nf = 0; nf < 2; ++nf)
            bb[nf] = *(const f16x8*)&Bs[wn * 32 + nf * 16 + (lane & 15)][(lane >> 4) * 8];
#pragma unroll
        for (int mf = 0; mf < 4; ++mf)
#pragma unroll
            for (int nf = 0; nf < 2; ++nf)
                acc[mf][nf] = __builtin_amdgcn_mfma_f32_16x16x32_f16(a[mf], bb[nf], acc[mf][nf], 0, 0, 0);
        __syncthreads();
    }
#pragma unroll
    for (int mf = 0; mf < 4; ++mf)
#pragma unroll
        for (int nf = 0; nf < 2; ++nf) {
            int rowb = m0 + wm * 64 + mf * 16 + (lane >> 4) * 4;
            int col = n0 + wn * 32 + nf * 16 + (lane & 15);
            float bv = bias[col];
#pragma unroll
            for (int rg = 0; rg < 4; ++rg)
                outf[(size_t)(rowb + rg) * Dc + col] = acc[mf][nf][rg] + bv;
        }
}

// ---------------------------------------------------------------------------
extern "C" void kernel_launch(void* const* d_in, const int* in_sizes, int n_in,
                              void* d_out, int out_size, void* d_ws, size_t ws_size,
                              hipStream_t stream) {
    const float* hid = (const float*)d_in[0];
    const float* rel_q = (const float*)d_in[1];
    const float* rel_k = (const float*)d_in[2];
    const float* Wq = (const float*)d_in[3];
    const float* bq = (const float*)d_in[4];
    const float* Wk = (const float*)d_in[5];
    const float* bk = (const float*)d_in[6];
    const float* Wv = (const float*)d_in[7];
    const float* bv = (const float*)d_in[8];
    const float* Wo = (const float*)d_in[9];
    const float* bo = (const float*)d_in[10];
    const int* pos = (const int*)d_in[11];
    const int* mask = (const int*)d_in[12];

    const size_t MiB = 1ull << 20;
    const size_t tblBytes = (size_t)Bc * Hc * Rc * Lc * 2;  // 8,519,680
    const size_t opBytes = (size_t)Bc * Lc * Dc * 2;        // 4 MiB per slot
    const size_t mlBytes = (size_t)Bc * Hc * Lc * 8;        // 256 KiB per slot
    const size_t need = (12 + 18 + 13) * MiB + 65536;
    if (need > ws_size) return;  // diagnostic signature: absmax == max|ref|

    char* ws = (char*)d_ws;
    size_t off = 0;
    auto alloc = [&](size_t bytes) {
        void* p = ws + off;
        off += (bytes + 255) & ~(size_t)255;
        return p;
    };

    f16* qw = (f16*)alloc(opBytes);
    f16* kw = (f16*)alloc(opBytes);
    f16* vtw = (f16*)alloc(opBytes);
    // tables stay live while attn_v10 runs -> separate region
    f16* c2pTw = (f16*)alloc(tblBytes);
    f16* p2cw = (f16*)alloc(tblBytes);
    // partials (2 slots) + ctx
    char* u = (char*)alloc(13 * MiB);
    f16* oparts = (f16*)u;
    float2* mls = (float2*)(u + 2 * opBytes);
    f16* ctxh = (f16*)(u + 2 * (opBytes + mlBytes));

    gemm_qkv<<<dim3(24, 16), 256, 0, stream>>>(hid, Wq, Wk, Wv, bq, bk, bv, qw, kw, vtw);
    rel_mfma<<<dim3(16, 32, 2), 256, 0, stream>>>(qw, kw, rel_k, rel_q, c2pTw, p2cw, mask);
    attn_v10<<<512, 512, 0, stream>>>(qw, kw, vtw, p2cw, c2pTw, pos, oparts, mls);
    merge_ns<<<2048, 256, 0, stream>>>(oparts, mls, ctxh, 2);
    gemm_out<<<dim3(16, 16), 256, 0, stream>>>(ctxh, Wo, bo, (float*)d_out);
}

// Round 21
// 130.351 us; speedup vs baseline: 1.0414x; 1.0414x over previous
//
#include <hip/hip_runtime.h>
#include <hip/hip_fp16.h>

typedef _Float16 f16;
typedef f16 f16x8 __attribute__((ext_vector_type(8)));
typedef f16 f16x4 __attribute__((ext_vector_type(4)));
typedef f16 f16x2 __attribute__((ext_vector_type(2)));
typedef float f32x4 __attribute__((ext_vector_type(4)));

#define DEVI static __device__ __forceinline__

constexpr int Bc = 2, Lc = 1024, Dc = 1024, Hc = 16, DKc = 64, Rc = 130;
constexpr float SCALE = 0.07216878364870323f; // 1/sqrt(64*3)
constexpr float MASKV = -30000.0f;            // f16-safe "-inf" (f16-exact)

DEVI uint2 pack8(int4 a, int4 b) {
    unsigned lo = (unsigned)(a.x & 255) | ((unsigned)(a.y & 255) << 8) |
                  ((unsigned)(a.z & 255) << 16) | ((unsigned)(a.w & 255) << 24);
    unsigned hi = (unsigned)(b.x & 255) | ((unsigned)(b.y & 255) << 8) |
                  ((unsigned)(b.z & 255) << 16) | ((unsigned)(b.w & 255) << 24);
    return make_uint2(lo, hi);
}

DEVI int i4get(const int4& v, int u) {  // compile-time u under unroll -> no scratch
    return u == 0 ? v.x : (u == 1 ? v.y : (u == 2 ? v.z : v.w));
}

DEVI int packf16(float a, float b) {
    f16x2 t = {(f16)a, (f16)b};
    return __builtin_bit_cast(int, t);
}

// ---------------------------------------------------------------------------
// Fused QKV GEMM, f32 inputs staged to f16 LDS (L3 absorbs tile re-reads).
// q pre-scaled by SCALE. q/k -> [B,H,L,DK]; v -> [B,H,DK,L] transposed.
// Tile 128x64, BK=32, 4 waves (2x2).
// ---------------------------------------------------------------------------
__global__ __launch_bounds__(256) void gemm_qkv(const float* __restrict__ A,
                                                const float* __restrict__ wq,
                                                const float* __restrict__ wk,
                                                const float* __restrict__ wv,
                                                const float* __restrict__ bq,
                                                const float* __restrict__ bk,
                                                const float* __restrict__ bv,
                                                f16* __restrict__ qw,
                                                f16* __restrict__ kw,
                                                f16* __restrict__ vtw) {
    constexpr int K = 1024;
    __shared__ __align__(16) f16 As[128][40];
    __shared__ __align__(16) f16 Bs[64][40];
    const int tid = threadIdx.x, lane = tid & 63, w = tid >> 6;
    const int wm = w >> 1, wn = w & 1;
    const int m0 = blockIdx.y * 128, n0 = blockIdx.x * 64;
    const int which = n0 >> 10;  // 0=q 1=k 2=v (uniform per block)
    const float* __restrict__ W = which == 0 ? wq : (which == 1 ? wk : wv);
    const int n0L = n0 & 1023;

    f32x4 acc[4][2];
#pragma unroll
    for (int i = 0; i < 4; ++i)
#pragma unroll
        for (int j = 0; j < 2; ++j) acc[i][j] = (f32x4){0.f, 0.f, 0.f, 0.f};

    for (int k0 = 0; k0 < K; k0 += 32) {
#pragma unroll
        for (int rep = 0; rep < 4; ++rep) {  // A 128x32 f32 -> f16
            int id = tid + rep * 256;
            int row = id >> 3, c = (id & 7) * 4;
            float4 v = *(const float4*)&A[(size_t)(m0 + row) * K + k0 + c];
            *(f16x4*)&As[row][c] = (f16x4){(f16)v.x, (f16)v.y, (f16)v.z, (f16)v.w};
        }
#pragma unroll
        for (int rep = 0; rep < 2; ++rep) {  // W 64x32 f32 -> f16
            int id = tid + rep * 256;
            int row = id >> 3, c = (id & 7) * 4;
            float4 v = *(const float4*)&W[(size_t)(n0L + row) * K + k0 + c];
            *(f16x4*)&Bs[row][c] = (f16x4){(f16)v.x, (f16)v.y, (f16)v.z, (f16)v.w};
        }
        __syncthreads();
        f16x8 a[4], bb[2];
#pragma unroll
        for (int mf = 0; mf < 4; ++mf)
            a[mf] = *(const f16x8*)&As[wm * 64 + mf * 16 + (lane & 15)][(lane >> 4) * 8];
#pragma unroll
        for (int nf = 0; nf < 2; ++nf)
            bb[nf] = *(const f16x8*)&Bs[wn * 32 + nf * 16 + (lane & 15)][(lane >> 4) * 8];
#pragma unroll
        for (int mf = 0; mf < 4; ++mf)
#pragma unroll
            for (int nf = 0; nf < 2; ++nf)
                acc[mf][nf] = __builtin_amdgcn_mfma_f32_16x16x32_f16(a[mf], bb[nf], acc[mf][nf], 0, 0, 0);
        __syncthreads();
    }

    const float* bp = which == 0 ? bq : (which == 1 ? bk : bv);
    const float scl = which == 0 ? SCALE : 1.0f;
#pragma unroll
    for (int mf = 0; mf < 4; ++mf)
#pragma unroll
        for (int nf = 0; nf < 2; ++nf) {
            int rowb = m0 + wm * 64 + mf * 16 + (lane >> 4) * 4;
            int col = n0 + wn * 32 + nf * 16 + (lane & 15);
            int colL = col & 1023;
            int h = colL >> 6, d = colL & 63;
            float bv_ = bp[colL];
            if (which == 2) {
                int b = rowb >> 10, i = rowb & (Lc - 1);
                f16x4 pk = {(f16)(acc[mf][nf][0] + bv_), (f16)(acc[mf][nf][1] + bv_),
                            (f16)(acc[mf][nf][2] + bv_), (f16)(acc[mf][nf][3] + bv_)};
                *(f16x4*)&vtw[(((size_t)(b * Hc + h)) * DKc + d) * Lc + i] = pk;
            } else {
                f16* dst = which ? kw : qw;
#pragma unroll
                for (int rg = 0; rg < 4; ++rg) {
                    int row = rowb + rg;
                    int b = row >> 10, i = row & (Lc - 1);
                    dst[(((size_t)(b * Hc + h)) * Lc + i) * DKc + d] =
                        (f16)((acc[mf][nf][rg] + bv_) * scl);
                }
            }
        }
}

// ---------------------------------------------------------------------------
// rel tables via MFMA: outT[(bh*R+r)*L+i] = scl * dot(rowmat[bh,i,:], relmat[h,r,:])
//                      (+ MASKV per masked column when mask != nullptr)
// grid (L/64, B*H). rowmat may be pre-scaled (then scl=1).
// ---------------------------------------------------------------------------
__global__ __launch_bounds__(256) void rel_mfma(const f16* __restrict__ rowmat,
                                                const float* __restrict__ relmat,
                                                f16* __restrict__ outT, float scl,
                                                const int* __restrict__ mask) {
    __shared__ __align__(16) f16 As[144][72];
    __shared__ __align__(16) f16 Bs[64][72];
    const int tid = threadIdx.x, lane = tid & 63, w = tid >> 6;
    const int bh = blockIdx.y, h = bh & (Hc - 1);
    const int i0 = blockIdx.x * 64;
    const size_t bhR = (size_t)bh * Rc;

    for (int e = tid; e < Rc * 16; e += 256) {
        int r = e >> 4, c = (e & 15) * 4;
        float4 v = *(const float4*)&relmat[((size_t)h * Rc + r) * DKc + c];
        *(f16x4*)&As[r][c] = (f16x4){(f16)v.x, (f16)v.y, (f16)v.z, (f16)v.w};
    }
    if (tid < 224) {
        int r = 130 + (tid >> 4), c = (tid & 15) * 4;
        *(f16x4*)&As[r][c] = (f16x4){(f16)0.f, (f16)0.f, (f16)0.f, (f16)0.f};
    }
    for (int e = tid; e < 64 * 8; e += 256) {
        int i = e >> 3, c = (e & 7) * 8;
        *(f16x8*)&Bs[i][c] = *(const f16x8*)&rowmat[((size_t)bh * Lc + i0 + i) * DKc + c];
    }
    __syncthreads();

    // per-thread output column; mask-fold value (p2c table only)
    const int ocol = i0 + w * 16 + (lane & 15);
    float ma = 0.f;
    if (mask) ma = mask[(bh >> 4) * Lc + ocol] ? MASKV : 0.f;

    f16x8 bfr[2];
#pragma unroll
    for (int ks = 0; ks < 2; ++ks)
        bfr[ks] = *(const f16x8*)&Bs[w * 16 + (lane & 15)][ks * 32 + (lane >> 4) * 8];
    f32x4 acc[9];
#pragma unroll
    for (int m = 0; m < 9; ++m) acc[m] = (f32x4){0.f, 0.f, 0.f, 0.f};
#pragma unroll
    for (int m = 0; m < 9; ++m)
#pragma unroll
        for (int ks = 0; ks < 2; ++ks) {
            f16x8 af = *(const f16x8*)&As[m * 16 + (lane & 15)][ks * 32 + (lane >> 4) * 8];
            acc[m] = __builtin_amdgcn_mfma_f32_16x16x32_f16(af, bfr[ks], acc[m], 0, 0, 0);
        }
#pragma unroll
    for (int m = 0; m < 9; ++m)
#pragma unroll
        for (int rg = 0; rg < 4; ++rg) {
            int r = m * 16 + (lane >> 4) * 4 + rg;
            if (r < Rc)
                outT[(bhR + r) * Lc + ocol] = (f16)(acc[m][rg] * scl + ma);
        }
}

// ---------------------------------------------------------------------------
// attn_v10: fused gather+flash, K/V cooperative dbuf LDS staging, P
// redistribution via shfl, mask folded into p2c, exact defer-rescale,
// setprio on MFMA clusters. XCD-aware flat grid: flat = ib*64 + sp*32 + bh.
// ---------------------------------------------------------------------------
__global__ __launch_bounds__(512) void attn_v10(const f16* __restrict__ q,
                                                const f16* __restrict__ k,
                                                const f16* __restrict__ vt,
                                                const f16* __restrict__ p2c,
                                                const f16* __restrict__ c2pT,
                                                const int* __restrict__ pos,
                                                f16* __restrict__ opart,
                                                float2* __restrict__ mlpart) {
    __shared__ f16 tc2p[Rc][132];               // [r][i-local 0..127] 34.3KB
    __shared__ f16 tp2c[2][Rc][36];             // [r][j-local], dbuf  18.7KB
    __shared__ __align__(16) f16 Ks[2][32][72]; // K tile, dbuf         9.2KB
    __shared__ __align__(16) f16 Vs[2][64][40]; // V tile, dbuf        10.2KB
    __shared__ unsigned char pJI[2][32][136];   // [j][i], dbuf         8.7KB

    const int tid = threadIdx.x, lane = tid & 63, w = tid >> 6;
    const int flat = blockIdx.x;
    const int ib = flat >> 6;            // 0..7
    const int sp = (flat >> 5) & 1;      // 0..1
    const int bh = flat & 31;            // 0..31
    const int b = bh >> 4, h = bh & 15;
    const int i0 = ib * 128;
    const int j0base = sp * 512;
    const size_t bhL = (size_t)bh * Lc;
    const size_t bhR = (size_t)bh * Rc;
    f16* __restrict__ op = opart + (size_t)sp * Bc * Lc * Dc;
    float2* __restrict__ mlp = mlpart + (size_t)sp * Bc * Hc * Lc;
    const int g = lane >> 4, il16 = lane & 15, irow = w * 16 + il16;

    // block-lifetime: tc2p [130][128]
    for (int e = tid; e < Rc * 32; e += 512) {
        int r = e >> 5, c4 = (e & 31) * 4;
        *(f16x4*)&tc2p[r][c4] = *(const f16x4*)&c2pT[(bhR + r) * Lc + i0 + c4];
    }

    // Q fragments (B-operand of swapped QK^T)
    f16x8 qa[2];
    {
        const f16* qp = &q[(bhL + i0 + irow) * DKc + g * 8];
        qa[0] = *(const f16x8*)qp;
        qa[1] = *(const f16x8*)(qp + 32);
    }

    float mrun = -1e30f, lrun = 0.f;
    f32x4 oacc[4];
#pragma unroll
    for (int df = 0; df < 4; ++df) oacc[df] = (f32x4){0.f, 0.f, 0.f, 0.f};

    // register pipeline state
    f16x4 kreg, vreg;                    // cooperative K/V stage (4KB each)
    int4 prA0, prA1, prB0, prB1;         // own-row pos (r1)
    f16x4 tpr0, tpr1, tpr2;              // tp2c staging regs
    uint2 pjreg;                         // pJI staging

#define FV_ISSUE(J0X)                                                                        \
    {                                                                                        \
        kreg = *(const f16x4*)&k[(bhL + (J0X) + (tid >> 4)) * DKc + (tid & 15) * 4];         \
        vreg = *(const f16x4*)&vt[((size_t)bh * DKc + (tid >> 3)) * Lc + (J0X) + (tid & 7) * 4]; \
        {                                                                                    \
            int e_ = tid;                                                                    \
            tpr0 = *(const f16x4*)&p2c[(bhR + (e_ >> 3)) * Lc + (J0X) + (e_ & 7) * 4];       \
            e_ = tid + 512;                                                                  \
            tpr1 = *(const f16x4*)&p2c[(bhR + (e_ >> 3)) * Lc + (J0X) + (e_ & 7) * 4];       \
            if (tid < 16) {                                                                  \
                e_ = tid + 1024;                                                             \
                tpr2 = *(const f16x4*)&p2c[(bhR + (e_ >> 3)) * Lc + (J0X) + (e_ & 7) * 4];   \
            }                                                                                \
        }                                                                                    \
        {                                                                                    \
            const int* pp = &pos[(bhL + (J0X) + (tid >> 4)) * Lc + i0 + (tid & 15) * 8];     \
            pjreg = pack8(*(const int4*)pp, *(const int4*)(pp + 4));                         \
        }                                                                                    \
        {                                                                                    \
            const int* prow = &pos[(bhL + i0 + irow) * Lc + (J0X) + g * 4];                  \
            prB0 = *(const int4*)prow;                                                       \
            prB1 = *(const int4*)(prow + 16);                                                \
        }                                                                                    \
    }

#define FV_COMMIT(NB)                                                                        \
    {                                                                                        \
        *(f16x4*)&Ks[NB][tid >> 4][(tid & 15) * 4] = kreg;                                   \
        *(f16x4*)&Vs[NB][tid >> 3][(tid & 7) * 4] = vreg;                                    \
        int e_ = tid;                                                                        \
        *(f16x4*)&tp2c[NB][e_ >> 3][(e_ & 7) * 4] = tpr0;                                    \
        e_ = tid + 512;                                                                      \
        *(f16x4*)&tp2c[NB][e_ >> 3][(e_ & 7) * 4] = tpr1;                                    \
        if (tid < 16) { e_ = tid + 1024; *(f16x4*)&tp2c[NB][e_ >> 3][(e_ & 7) * 4] = tpr2; } \
        *(uint2*)&pJI[NB][tid >> 4][(tid & 15) * 8] = pjreg;                                 \
    }

    // prologue: tile 0
    FV_ISSUE(j0base);
    FV_COMMIT(0);
    prA0 = prB0; prA1 = prB1;
    __syncthreads();

    for (int t = 0; t < 16; ++t) {
        const int cur = t & 1;
        const int j0 = j0base + t * 32;
        if (t < 15) FV_ISSUE(j0 + 32);

        // QK^T swapped: mfma(A=K from LDS, B=Q)
        f32x4 s[2];
        s[0] = (f32x4){0.f, 0.f, 0.f, 0.f};
        s[1] = (f32x4){0.f, 0.f, 0.f, 0.f};
        __builtin_amdgcn_s_setprio(1);
#pragma unroll
        for (int jf = 0; jf < 2; ++jf)
#pragma unroll
            for (int ks = 0; ks < 2; ++ks) {
                f16x8 kb = *(const f16x8*)&Ks[cur][jf * 16 + il16][ks * 32 + g * 8];
                s[jf] = __builtin_amdgcn_mfma_f32_16x16x32_f16(kb, qa[ks], s[jf], 0, 0, 0);
            }
        __builtin_amdgcn_s_setprio(0);

        // score assembly: r1 from registers, r2 + tables from LDS (mask folded)
        float sv[8];
#pragma unroll
        for (int u = 0; u < 8; ++u) {
            int jcol = (u < 4) ? (g * 4 + u) : (16 + g * 4 + (u - 4));
            int r1 = (u < 4) ? i4get(prA0, u) : i4get(prA1, u - 4);
            int r2 = pJI[cur][jcol][irow];
            sv[u] = s[u >> 2][u & 3] + (float)tp2c[cur][r1][jcol] + (float)tc2p[r2][irow];
        }

        // per-lane-row online softmax with exact defer-rescale
        float tm = sv[0];
#pragma unroll
        for (int e = 1; e < 8; ++e) tm = fmaxf(tm, sv[e]);
        tm = fmaxf(tm, __shfl_xor(tm, 16));
        tm = fmaxf(tm, __shfl_xor(tm, 32));
        if (__any(tm > mrun)) {
            float mnew = fmaxf(mrun, tm);
            float alpha = __expf(mrun - mnew);
            mrun = mnew;
            lrun *= alpha;
            float al[4];
#pragma unroll
            for (int rg = 0; rg < 4; ++rg)
                al[rg] = __shfl(alpha, (lane & 48) | (g * 4 + rg));
#pragma unroll
            for (int df = 0; df < 4; ++df)
#pragma unroll
                for (int rg = 0; rg < 4; ++rg) oacc[df][rg] *= al[rg];
        }
        float rs = 0.f;
#pragma unroll
        for (int e = 0; e < 8; ++e) {
            sv[e] = __expf(sv[e] - mrun);
            rs += sv[e];
        }
        rs += __shfl_xor(rs, 16);
        rs += __shfl_xor(rs, 32);
        lrun += rs;

        // P fragment redistribution via shfl (lane (g,il16) needs P[il16][g*8..+7])
        int lo0 = packf16(sv[0], sv[1]), lo1 = packf16(sv[2], sv[3]);
        int hi0 = packf16(sv[4], sv[5]), hi1 = packf16(sv[6], sv[7]);
        int s0 = ((g & 1) << 5) | il16, s1 = s0 + 16;
        int a0 = __shfl(lo0, s0), a1 = __shfl(lo1, s0);
        int a2 = __shfl(lo0, s1), a3 = __shfl(lo1, s1);
        int b0 = __shfl(hi0, s0), b1 = __shfl(hi1, s0);
        int b2 = __shfl(hi0, s1), b3 = __shfl(hi1, s1);
        int4 paw = (g < 2) ? make_int4(a0, a1, a2, a3) : make_int4(b0, b1, b2, b3);
        f16x8 pa = __builtin_bit_cast(f16x8, paw);

        // PV: A = P frags (regs), B = V tile (LDS)
        __builtin_amdgcn_s_setprio(1);
#pragma unroll
        for (int df = 0; df < 4; ++df) {
            f16x8 vb = *(const f16x8*)&Vs[cur][df * 16 + il16][g * 8];
            oacc[df] = __builtin_amdgcn_mfma_f32_16x16x32_f16(pa, vb, oacc[df], 0, 0, 0);
        }
        __builtin_amdgcn_s_setprio(0);

        if (t < 15) {
            FV_COMMIT(cur ^ 1);
            prA0 = prB0; prA1 = prB1;
        }
        __syncthreads();
    }

    // unnormalized partial (f16) + (m,l)
#pragma unroll
    for (int df = 0; df < 4; ++df)
#pragma unroll
        for (int rg = 0; rg < 4; ++rg) {
            int i = i0 + w * 16 + g * 4 + rg;
            int d = df * 16 + il16;
            op[((size_t)(b * Lc + i) * Hc + h) * DKc + d] = (f16)oacc[df][rg];
        }
    if (g == 0) mlp[bhL + i0 + irow] = make_float2(mrun, lrun);
#undef FV_ISSUE
#undef FV_COMMIT
}

// ---------------------------------------------------------------------------
// merge ns partial slots -> ctx f16 (f16x4 per thread)
// ---------------------------------------------------------------------------
__global__ __launch_bounds__(256) void merge_ns(const f16* __restrict__ op,
                                                const float2* __restrict__ ml,
                                                f16* __restrict__ ctx, int ns) {
    int t4 = blockIdx.x * 256 + threadIdx.x;  // 4-elem index, total 524288
    int t = t4 * 4;
    int b = t >> 20;
    int rem = t & 1048575;
    int i = rem >> 10;
    int h = (rem & 1023) >> 6;
    int row = ((b << 4) + h) * Lc + i;
    const size_t On = (size_t)Bc * Lc * Dc, Mn = (size_t)Bc * Hc * Lc;
    float mx = -1e30f;
    for (int s = 0; s < ns; ++s) mx = fmaxf(mx, ml[s * Mn + row].x);
    float l = 0.f;
    float v[4] = {0.f, 0.f, 0.f, 0.f};
    for (int s = 0; s < ns; ++s) {
        float2 m = ml[s * Mn + row];
        float w_ = __expf(m.x - mx);
        l += m.y * w_;
        f16x4 o = *(const f16x4*)&op[s * On + t];
#pragma unroll
        for (int e = 0; e < 4; ++e) v[e] += (float)o[e] * w_;
    }
    float rl = 1.0f / l;
    f16x4 r = {(f16)(v[0] * rl), (f16)(v[1] * rl), (f16)(v[2] * rl), (f16)(v[3] * rl)};
    *(f16x4*)&ctx[t] = r;
}

// ---------------------------------------------------------------------------
// out-proj GEMM: A f16, W f32 (staged to f16) -> f32 out
// ---------------------------------------------------------------------------
__global__ __launch_bounds__(256) void gemm_out(const f16* __restrict__ A,
                                                const float* __restrict__ W,
                                                const float* __restrict__ bias,
                                                float* __restrict__ outf) {
    constexpr int K = 1024;
    __shared__ __align__(16) f16 As[128][40];
    __shared__ __align__(16) f16 Bs[64][40];
    const int tid = threadIdx.x, lane = tid & 63, w = tid >> 6;
    const int wm = w >> 1, wn = w & 1;
    const int m0 = blockIdx.y * 128, n0 = blockIdx.x * 64;

    f32x4 acc[4][2];
#pragma unroll
    for (int i = 0; i < 4; ++i)
#pragma unroll
        for (int j = 0; j < 2; ++j) acc[i][j] = (f32x4){0.f, 0.f, 0.f, 0.f};

    for (int k0 = 0; k0 < K; k0 += 32) {
#pragma unroll
        for (int rep = 0; rep < 2; ++rep) {
            int id = tid + rep * 256;
            int row = id >> 2, c = (id & 3) * 8;
            *(f16x8*)&As[row][c] = *(const f16x8*)&A[(size_t)(m0 + row) * K + k0 + c];
        }
#pragma unroll
        for (int rep = 0; rep < 2; ++rep) {  // W 64x32 f32 -> f16
            int id = tid + rep * 256;
            int row = id >> 3, c = (id & 7) * 4;
            float4 v = *(const float4*)&W[(size_t)(n0 + row) * K + k0 + c];
            *(f16x4*)&Bs[row][c] = (f16x4){(f16)v.x, (f16)v.y, (f16)v.z, (f16)v.w};
        }
        __syncthreads();
        f16x8 a[4], bb[2];
#pragma unroll
        for (int mf = 0; mf < 4; ++mf)
            a[mf] = *(const f16x8*)&As[wm * 64 + mf * 16 + (lane & 15)][(lane >> 4) * 8];
#pragma unroll
        for (int nf = 0; nf < 2; ++nf)
            bb[nf] = *(const f16x8*)&Bs[wn * 32 + nf * 16 + (lane & 15)][(lane >> 4) * 8];
#pragma unroll
        for (int mf = 0; mf < 4; ++mf)
#pragma unroll
            for (int nf = 0; nf < 2; ++nf)
                acc[mf][nf] = __builtin_amdgcn_mfma_f32_16x16x32_f16(a[mf], bb[nf], acc[mf][nf], 0, 0, 0);
        __syncthreads();
    }
#pragma unroll
    for (int mf = 0; mf < 4; ++mf)
#pragma unroll
        for (int nf = 0; nf < 2; ++nf) {
            int rowb = m0 + wm * 64 + mf * 16 + (lane >> 4) * 4;
            int col = n0 + wn * 32 + nf * 16 + (lane & 15);
            float bv = bias[col];
#pragma unroll
            for (int rg = 0; rg < 4; ++rg)
                outf[(size_t)(rowb + rg) * Dc + col] = acc[mf][nf][rg] + bv;
        }
}

// ---------------------------------------------------------------------------
extern "C" void kernel_launch(void* const* d_in, const int* in_sizes, int n_in,
                              void* d_out, int out_size, void* d_ws, size_t ws_size,
                              hipStream_t stream) {
    const float* hid = (const float*)d_in[0];
    const float* rel_q = (const float*)d_in[1];
    const float* rel_k = (const float*)d_in[2];
    const float* Wq = (const float*)d_in[3];
    const float* bq = (const float*)d_in[4];
    const float* Wk = (const float*)d_in[5];
    const float* bk = (const float*)d_in[6];
    const float* Wv = (const float*)d_in[7];
    const float* bv = (const float*)d_in[8];
    const float* Wo = (const float*)d_in[9];
    const float* bo = (const float*)d_in[10];
    const int* pos = (const int*)d_in[11];
    const int* mask = (const int*)d_in[12];

    const size_t MiB = 1ull << 20;
    const size_t tblBytes = (size_t)Bc * Hc * Rc * Lc * 2;  // 8,519,680
    const size_t opBytes = (size_t)Bc * Lc * Dc * 2;        // 4 MiB per slot
    const size_t mlBytes = (size_t)Bc * Hc * Lc * 8;        // 256 KiB per slot
    const size_t need = (12 + 18 + 13) * MiB + 65536;
    if (need > ws_size) return;  // diagnostic signature: absmax == max|ref|

    char* ws = (char*)d_ws;
    size_t off = 0;
    auto alloc = [&](size_t bytes) {
        void* p = ws + off;
        off += (bytes + 255) & ~(size_t)255;
        return p;
    };

    f16* qw = (f16*)alloc(opBytes);
    f16* kw = (f16*)alloc(opBytes);
    f16* vtw = (f16*)alloc(opBytes);
    // tables stay live while attn_v10 runs -> separate region
    f16* c2pTw = (f16*)alloc(tblBytes);
    f16* p2cw = (f16*)alloc(tblBytes);
    // partials (2 slots) + ctx
    char* u = (char*)alloc(13 * MiB);
    f16* oparts = (f16*)u;
    float2* mls = (float2*)(u + 2 * opBytes);
    f16* ctxh = (f16*)(u + 2 * (opBytes + mlBytes));

    gemm_qkv<<<dim3(48, 16), 256, 0, stream>>>(hid, Wq, Wk, Wv, bq, bk, bv, qw, kw, vtw);
    rel_mfma<<<dim3(16, 32), 256, 0, stream>>>(qw, rel_k, c2pTw, 1.0f, nullptr);  // q pre-scaled
    rel_mfma<<<dim3(16, 32), 256, 0, stream>>>(kw, rel_q, p2cw, SCALE, mask);     // mask folded
    attn_v10<<<512, 512, 0, stream>>>(qw, kw, vtw, p2cw, c2pTw, pos, oparts, mls);
    merge_ns<<<2048, 256, 0, stream>>>(oparts, mls, ctxh, 2);
    gemm_out<<<dim3(16, 16), 256, 0, stream>>>(ctxh, Wo, bo, (float*)d_out);
}